// Round 1
// baseline (125.179 us; speedup 1.0000x reference)
//
#include <hip/hip_runtime.h>

typedef _Float16 f16x8 __attribute__((ext_vector_type(8)));
typedef _Float16 f16x4 __attribute__((ext_vector_type(4)));
typedef float    f32x4 __attribute__((ext_vector_type(4)));

// ---------------- workspace layout (bytes) ----------------
#define A16_OFF   0u
#define V16_OFF   16777216u
#define WAT_OFF   33554432u
#define WVT_OFF   33947648u
#define CORRT_OFF 34340864u
#define WBT_OFF   34471936u

// =========================================================
// k_tr: transpose + fp32->fp16 convert of the weight mats.
//  Wa [768,256]->WaT [256,768]; Wv same; corr[256,256]->corrT;
//  Wb [512,64]->WbT [64,512].
// =========================================================
__global__ __launch_bounds__(256) void k_tr(
    const float* __restrict__ Wa, const float* __restrict__ Wv,
    const float* __restrict__ corr, const float* __restrict__ Wb,
    _Float16* __restrict__ WaT, _Float16* __restrict__ WvT,
    _Float16* __restrict__ corrT, _Float16* __restrict__ WbT)
{
    __shared__ _Float16 tile[64][72];
    int bid = blockIdx.x;
    const float* src; _Float16* dst; int R, C, tr, tc;
    if (bid < 48)       { src = Wa;   dst = WaT;   R = 768; C = 256; int i = bid;       tr = i >> 2; tc = i & 3; }
    else if (bid < 96)  { src = Wv;   dst = WvT;   R = 768; C = 256; int i = bid - 48;  tr = i >> 2; tc = i & 3; }
    else if (bid < 112) { src = corr; dst = corrT; R = 256; C = 256; int i = bid - 96;  tr = i >> 2; tc = i & 3; }
    else                { src = Wb;   dst = WbT;   R = 512; C = 64;  int i = bid - 112; tr = i;      tc = 0;     }
    int r0 = tr * 64, c0 = tc * 64;
    int t = threadIdx.x;
    #pragma unroll
    for (int it = 0; it < 16; ++it) {
        int idx = t + it * 256;
        int r = idx >> 6, c = idx & 63;
        tile[r][c] = (_Float16)src[(size_t)(r0 + r) * C + (c0 + c)];
    }
    __syncthreads();
    #pragma unroll
    for (int it = 0; it < 16; ++it) {
        int idx = t + it * 256;
        int c = idx >> 6, r = idx & 63;
        dst[(size_t)(c0 + c) * R + (r0 + r)] = tile[r][c];
    }
}

// =========================================================
// k_proj: a = Xa@Wa+ba (z=0), v = Xv@Wv+bv (z=1), fp16 out.
//  M=32768, N=256, K=768. Tile: BM=128, BN=256, BK=64.
//  4 waves: wave covers 64x128. grid (256,1,2).
// =========================================================
__global__ __launch_bounds__(256) void k_proj(
    const float* __restrict__ Xa, const float* __restrict__ Xv,
    const _Float16* __restrict__ WaT, const _Float16* __restrict__ WvT,
    const float* __restrict__ ba, const float* __restrict__ bv,
    _Float16* __restrict__ Aout, _Float16* __restrict__ Vout)
{
    __shared__ _Float16 As[128 * 64];   // [row][k] xor-swizzled
    __shared__ _Float16 Bs[256 * 64];   // [n][k]   xor-swizzled

    const int z = blockIdx.z;
    const float*    X    = z ? Xv  : Xa;
    const _Float16* WT   = z ? WvT : WaT;
    const float*    bias = z ? bv  : ba;
    _Float16*       Out  = z ? Vout : Aout;

    const int m0 = blockIdx.x * 128;
    const int t = threadIdx.x;
    const int lane = t & 63, w = t >> 6;
    const int wr = w >> 1, wc = w & 1;
    const int q = lane >> 4, lm = lane & 15;

    f32x4 acc[4][8] = {};

    for (int ks = 0; ks < 12; ++ks) {
        const int k0 = ks * 64;
        // stage A: 128 rows x 64 k (fp32 -> fp16)
        #pragma unroll
        for (int it = 0; it < 8; ++it) {
            int idx = t + it * 256;
            int row = idx >> 4, kc = idx & 15;
            f32x4 xv = *reinterpret_cast<const f32x4*>(X + (size_t)(m0 + row) * 768 + k0 + kc * 4);
            f16x4 h = __builtin_convertvector(xv, f16x4);
            int byte = (row * 128 + kc * 8) ^ ((row & 7) << 4);
            *reinterpret_cast<f16x4*>(reinterpret_cast<char*>(As) + byte) = h;
        }
        // stage B: 256 n x 64 k (fp16)
        #pragma unroll
        for (int it = 0; it < 8; ++it) {
            int idx = t + it * 256;
            int n = idx >> 3, kc = idx & 7;
            f16x8 wv = *reinterpret_cast<const f16x8*>(WT + (size_t)n * 768 + k0 + kc * 8);
            int byte = (n * 128 + kc * 16) ^ ((n & 7) << 4);
            *reinterpret_cast<f16x8*>(reinterpret_cast<char*>(Bs) + byte) = wv;
        }
        __syncthreads();
        #pragma unroll
        for (int kk = 0; kk < 2; ++kk) {
            f16x8 af[4];
            #pragma unroll
            for (int mf = 0; mf < 4; ++mf) {
                int row = wr * 64 + mf * 16 + lm;
                int byte = (row * 128 + (kk * 32 + q * 8) * 2) ^ ((row & 7) << 4);
                af[mf] = *reinterpret_cast<const f16x8*>(reinterpret_cast<const char*>(As) + byte);
            }
            #pragma unroll
            for (int nf = 0; nf < 8; ++nf) {
                int n = wc * 128 + nf * 16 + lm;
                int byte = (n * 128 + (kk * 32 + q * 8) * 2) ^ ((n & 7) << 4);
                f16x8 bf = *reinterpret_cast<const f16x8*>(reinterpret_cast<const char*>(Bs) + byte);
                #pragma unroll
                for (int mf = 0; mf < 4; ++mf)
                    acc[mf][nf] = __builtin_amdgcn_mfma_f32_16x16x32_f16(af[mf], bf, acc[mf][nf], 0, 0, 0);
            }
        }
        __syncthreads();
    }
    // epilogue: + bias, store fp16
    #pragma unroll
    for (int nf = 0; nf < 8; ++nf) {
        int d = wc * 128 + nf * 16 + lm;
        float bia = bias[d];
        #pragma unroll
        for (int mf = 0; mf < 4; ++mf) {
            int rowb = m0 + wr * 64 + mf * 16 + q * 4;
            #pragma unroll
            for (int r = 0; r < 4; ++r)
                Out[(size_t)(rowb + r) * 256 + d] = (_Float16)(acc[mf][nf][r] + bia);
        }
    }
}

// =========================================================
// k_fuse: per-batch (512 blocks, 256 thr = 4 waves)
//  ac = a@corr ; cc = ac@v^T ; dual softmax (+I) ;
//  aw = a@Wb_top, vw = v@Wb_bot ;
//  h = attA^T@aw + attV@vw + bb ; LayerNorm ; ReLU.
// LDS (dynamic, 159232 B):
//  a_s[64][264] f16, v_s[64][264], ac_s[64][264],
//  cc_s[64][66] f32, attAT[64][72] f16 (att[i][j]+I stored [j][i]),
//  attV[64][72] ([i][j]), awT[64][72] ([o][i]), vwT[64][72] ([o][j]),
//  red[4][4][64] f32.
// =========================================================
#define SM_A    0u
#define SM_V    33792u
#define SM_AC   67584u
#define SM_CC   101376u
#define SM_ATA  118272u
#define SM_ATV  127488u
#define SM_AWT  136704u
#define SM_VWT  145920u
#define SM_RED  155136u
#define SM_TOTAL 159232u

__global__ __launch_bounds__(256) void k_fuse(
    const _Float16* __restrict__ A16, const _Float16* __restrict__ V16,
    const _Float16* __restrict__ corrT, const _Float16* __restrict__ WbT,
    const float* __restrict__ bb, const float* __restrict__ gamma,
    const float* __restrict__ beta, float* __restrict__ out)
{
    extern __shared__ char sm[];
    _Float16* a_s   = (_Float16*)(sm + SM_A);
    _Float16* v_s   = (_Float16*)(sm + SM_V);
    _Float16* ac_s  = (_Float16*)(sm + SM_AC);
    float*    cc_s  = (float*)(sm + SM_CC);
    _Float16* attAT = (_Float16*)(sm + SM_ATA);
    _Float16* attV  = (_Float16*)(sm + SM_ATV);
    _Float16* awT   = (_Float16*)(sm + SM_AWT);
    _Float16* vwT   = (_Float16*)(sm + SM_VWT);
    float*    red   = (float*)(sm + SM_RED);

    const int b = blockIdx.x;
    const int t = threadIdx.x, lane = t & 63, w = t >> 6;
    const int q = lane >> 4, lm = lane & 15;

    // ---- Phase A: stage a,v (fp16) into LDS (padded rows, stride 264) ----
    const _Float16* Ab = A16 + (size_t)b * 64 * 256;
    const _Float16* Vb = V16 + (size_t)b * 64 * 256;
    #pragma unroll
    for (int it = 0; it < 8; ++it) {
        int idx = t + it * 256;
        int row = idx >> 5, kc = idx & 31;
        *reinterpret_cast<f16x8*>(a_s + row * 264 + kc * 8) =
            *reinterpret_cast<const f16x8*>(Ab + row * 256 + kc * 8);
        *reinterpret_cast<f16x8*>(v_s + row * 264 + kc * 8) =
            *reinterpret_cast<const f16x8*>(Vb + row * 256 + kc * 8);
    }
    __syncthreads();

    // ---- Phase B: ac = a @ corr ; wave w owns e in [64w, 64w+64) ----
    {
        f32x4 acc[4][4] = {};
        for (int ks = 0; ks < 8; ++ks) {
            f16x8 af[4];
            #pragma unroll
            for (int mf = 0; mf < 4; ++mf)
                af[mf] = *reinterpret_cast<const f16x8*>(a_s + (mf * 16 + lm) * 264 + ks * 32 + q * 8);
            #pragma unroll
            for (int nf = 0; nf < 4; ++nf) {
                int e = w * 64 + nf * 16 + lm;
                f16x8 bf = *reinterpret_cast<const f16x8*>(corrT + (size_t)e * 256 + ks * 32 + q * 8);
                #pragma unroll
                for (int mf = 0; mf < 4; ++mf)
                    acc[mf][nf] = __builtin_amdgcn_mfma_f32_16x16x32_f16(af[mf], bf, acc[mf][nf], 0, 0, 0);
            }
        }
        #pragma unroll
        for (int mf = 0; mf < 4; ++mf)
            #pragma unroll
            for (int nf = 0; nf < 4; ++nf)
                #pragma unroll
                for (int r = 0; r < 4; ++r)
                    ac_s[(mf * 16 + 4 * q + r) * 264 + (w * 64 + nf * 16 + lm)] = (_Float16)acc[mf][nf][r];
    }
    __syncthreads();

    // ---- Phase C: cc = ac @ v^T ; wave w owns j-strip [16w, 16w+16) ----
    {
        f32x4 acc[4] = {};
        for (int ks = 0; ks < 8; ++ks) {
            f16x8 bf = *reinterpret_cast<const f16x8*>(v_s + (w * 16 + lm) * 264 + ks * 32 + q * 8);
            #pragma unroll
            for (int mf = 0; mf < 4; ++mf) {
                f16x8 af = *reinterpret_cast<const f16x8*>(ac_s + (mf * 16 + lm) * 264 + ks * 32 + q * 8);
                acc[mf] = __builtin_amdgcn_mfma_f32_16x16x32_f16(af, bf, acc[mf], 0, 0, 0);
            }
        }
        #pragma unroll
        for (int mf = 0; mf < 4; ++mf)
            #pragma unroll
            for (int r = 0; r < 4; ++r)
                cc_s[(mf * 16 + 4 * q + r) * 66 + (w * 16 + lm)] = acc[mf][r];
    }
    __syncthreads();

    // ---- Phase D: dual softmax (+identity). thread t: index j = t&63, segment = wave ----
    {
        int j = t & 63, seg = w;
        float cmx = -1e30f, rmx = -1e30f;
        #pragma unroll
        for (int k = 0; k < 16; ++k) {
            int i = seg * 16 + k;
            cmx = fmaxf(cmx, cc_s[i * 66 + j]);   // column j, rows i
            rmx = fmaxf(rmx, cc_s[j * 66 + i]);   // row j, cols i
        }
        red[0 * 256 + seg * 64 + j] = cmx;
        red[2 * 256 + seg * 64 + j] = rmx;
        __syncthreads();
        float cm = fmaxf(fmaxf(red[0 * 256 + 0 * 64 + j], red[0 * 256 + 1 * 64 + j]),
                         fmaxf(red[0 * 256 + 2 * 64 + j], red[0 * 256 + 3 * 64 + j]));
        float rm = fmaxf(fmaxf(red[2 * 256 + 0 * 64 + j], red[2 * 256 + 1 * 64 + j]),
                         fmaxf(red[2 * 256 + 2 * 64 + j], red[2 * 256 + 3 * 64 + j]));
        float cs = 0.f, rs = 0.f;
        #pragma unroll
        for (int k = 0; k < 16; ++k) {
            int i = seg * 16 + k;
            cs += __expf(cc_s[i * 66 + j] - cm);
            rs += __expf(cc_s[j * 66 + i] - rm);
        }
        red[1 * 256 + seg * 64 + j] = cs;
        red[3 * 256 + seg * 64 + j] = rs;
        __syncthreads();
        float csum = red[1 * 256 + 0 * 64 + j] + red[1 * 256 + 1 * 64 + j] +
                     red[1 * 256 + 2 * 64 + j] + red[1 * 256 + 3 * 64 + j];
        float rsum = red[3 * 256 + 0 * 64 + j] + red[3 * 256 + 1 * 64 + j] +
                     red[3 * 256 + 2 * 64 + j] + red[3 * 256 + 3 * 64 + j];
        float cinv = 1.f / csum, rinv = 1.f / rsum;
        #pragma unroll
        for (int k = 0; k < 16; ++k) {
            int i = seg * 16 + k;
            float pa = __expf(cc_s[i * 66 + j] - cm) * cinv;   // audio_att[i][j]
            if (i == j) pa += 1.f;
            attAT[j * 72 + i] = (_Float16)pa;                  // stored [j][i]
            float pv = __expf(cc_s[j * 66 + i] - rm) * rinv;   // visual_att[j][i]
            if (i == j) pv += 1.f;
            attV[j * 72 + i] = (_Float16)pv;                   // stored [row j][col i]
        }
    }

    // ---- Phase E: aw = a@Wb_top (waves 0,1), vw = v@Wb_bot (waves 2,3) ----
    {
        int isV = w >> 1, wcol = w & 1;
        const _Float16* src = isV ? v_s : a_s;
        const int doff = isV ? 256 : 0;
        f32x4 acc[4][2] = {};
        for (int ks = 0; ks < 8; ++ks) {
            f16x8 af[4];
            #pragma unroll
            for (int mf = 0; mf < 4; ++mf)
                af[mf] = *reinterpret_cast<const f16x8*>(src + (mf * 16 + lm) * 264 + ks * 32 + q * 8);
            #pragma unroll
            for (int nf = 0; nf < 2; ++nf) {
                int o = wcol * 32 + nf * 16 + lm;
                f16x8 bf = *reinterpret_cast<const f16x8*>(WbT + (size_t)o * 512 + doff + ks * 32 + q * 8);
                #pragma unroll
                for (int mf = 0; mf < 4; ++mf)
                    acc[mf][nf] = __builtin_amdgcn_mfma_f32_16x16x32_f16(af[mf], bf, acc[mf][nf], 0, 0, 0);
            }
        }
        _Float16* dst = isV ? vwT : awT;   // stored [o][i]
        #pragma unroll
        for (int mf = 0; mf < 4; ++mf)
            #pragma unroll
            for (int nf = 0; nf < 2; ++nf)
                #pragma unroll
                for (int r = 0; r < 4; ++r)
                    dst[(wcol * 32 + nf * 16 + lm) * 72 + (mf * 16 + 4 * q + r)] = (_Float16)acc[mf][nf][r];
    }
    __syncthreads();

    // ---- Phase F: h = attA^T@aw + attV@vw ; wave w owns rows s in [16w,16w+16) ----
    f32x4 hacc[4] = {};
    #pragma unroll
    for (int kk = 0; kk < 2; ++kk) {
        f16x8 a1 = *reinterpret_cast<const f16x8*>(attAT + (16 * w + lm) * 72 + kk * 32 + q * 8);
        f16x8 a2 = *reinterpret_cast<const f16x8*>(attV  + (16 * w + lm) * 72 + kk * 32 + q * 8);
        #pragma unroll
        for (int nf = 0; nf < 4; ++nf) {
            f16x8 b1 = *reinterpret_cast<const f16x8*>(awT + (nf * 16 + lm) * 72 + kk * 32 + q * 8);
            f16x8 b2 = *reinterpret_cast<const f16x8*>(vwT + (nf * 16 + lm) * 72 + kk * 32 + q * 8);
            hacc[nf] = __builtin_amdgcn_mfma_f32_16x16x32_f16(a1, b1, hacc[nf], 0, 0, 0);
            hacc[nf] = __builtin_amdgcn_mfma_f32_16x16x32_f16(a2, b2, hacc[nf], 0, 0, 0);
        }
    }

    // ---- Phase G: +bb, LayerNorm over o (64), *gamma+beta, ReLU, store ----
    {
        float bbv[4], gv[4], bev[4];
        #pragma unroll
        for (int nf = 0; nf < 4; ++nf) {
            int o = nf * 16 + lm;
            bbv[nf] = bb[o]; gv[nf] = gamma[o]; bev[nf] = beta[o];
        }
        #pragma unroll
        for (int r = 0; r < 4; ++r) {
            float vals[4]; float s1 = 0.f, s2 = 0.f;
            #pragma unroll
            for (int nf = 0; nf < 4; ++nf) {
                float hv = hacc[nf][r] + bbv[nf];
                vals[nf] = hv; s1 += hv; s2 += hv * hv;
            }
            #pragma unroll
            for (int m = 1; m < 16; m <<= 1) {
                s1 += __shfl_xor(s1, m, 64);
                s2 += __shfl_xor(s2, m, 64);
            }
            float mu = s1 * 0.015625f;
            float var = s2 * 0.015625f - mu * mu;
            float rstd = rsqrtf(var + 1e-5f);
            int s = 16 * w + 4 * q + r;
            float* orow = out + ((size_t)b * 64 + s) * 64;
            #pragma unroll
            for (int nf = 0; nf < 4; ++nf) {
                float y = (vals[nf] - mu) * rstd * gv[nf] + bev[nf];
                orow[nf * 16 + lm] = fmaxf(y, 0.f);
            }
        }
    }
}

// =========================================================
extern "C" void kernel_launch(void* const* d_in, const int* in_sizes, int n_in,
                              void* d_out, int out_size, void* d_ws, size_t ws_size,
                              hipStream_t stream) {
    const float* Xa    = (const float*)d_in[0];
    const float* Xv    = (const float*)d_in[1];
    const float* Wa    = (const float*)d_in[2];
    const float* ba    = (const float*)d_in[3];
    const float* Wv    = (const float*)d_in[4];
    const float* bv    = (const float*)d_in[5];
    const float* corr  = (const float*)d_in[6];
    const float* Wb    = (const float*)d_in[7];
    const float* bb    = (const float*)d_in[8];
    const float* gamma = (const float*)d_in[9];
    const float* beta  = (const float*)d_in[10];
    float* out = (float*)d_out;
    char* ws = (char*)d_ws;

    _Float16* a16   = (_Float16*)(ws + A16_OFF);
    _Float16* v16   = (_Float16*)(ws + V16_OFF);
    _Float16* WaT   = (_Float16*)(ws + WAT_OFF);
    _Float16* WvT   = (_Float16*)(ws + WVT_OFF);
    _Float16* corrT = (_Float16*)(ws + CORRT_OFF);
    _Float16* WbT   = (_Float16*)(ws + WBT_OFF);

    hipLaunchKernelGGL(k_tr, dim3(120), dim3(256), 0, stream,
                       Wa, Wv, corr, Wb, WaT, WvT, corrT, WbT);
    hipLaunchKernelGGL(k_proj, dim3(256, 1, 2), dim3(256), 0, stream,
                       Xa, Xv, WaT, WvT, ba, bv, a16, v16);
    (void)hipFuncSetAttribute((const void*)k_fuse,
                              hipFuncAttributeMaxDynamicSharedMemorySize, SM_TOTAL);
    hipLaunchKernelGGL(k_fuse, dim3(512), dim3(256), SM_TOTAL, stream,
                       a16, v16, corrT, WbT, bb, gamma, beta, out);
}

// Round 2
// 118.402 us; speedup vs baseline: 1.0572x; 1.0572x over previous
//
#include <hip/hip_runtime.h>

typedef _Float16 f16x8 __attribute__((ext_vector_type(8)));
typedef _Float16 f16x4 __attribute__((ext_vector_type(4)));
typedef float    f32x4 __attribute__((ext_vector_type(4)));

// ---------------- workspace layout (bytes) ----------------
#define A16_OFF   0u
#define V16_OFF   16777216u
#define WAT_OFF   33554432u
#define WVT_OFF   33947648u
#define CORRT_OFF 34340864u
#define WBT_OFF   34471936u

__device__ __forceinline__ void gl_lds16(const void* g, void* l) {
    __builtin_amdgcn_global_load_lds(
        (const __attribute__((address_space(1))) void*)g,
        (__attribute__((address_space(3))) void*)l,
        16, 0, 0);
}

// =========================================================
// k_tr: transpose + fp32->fp16 convert of the weight mats.
// =========================================================
__global__ __launch_bounds__(256) void k_tr(
    const float* __restrict__ Wa, const float* __restrict__ Wv,
    const float* __restrict__ corr, const float* __restrict__ Wb,
    _Float16* __restrict__ WaT, _Float16* __restrict__ WvT,
    _Float16* __restrict__ corrT, _Float16* __restrict__ WbT)
{
    __shared__ _Float16 tile[64][72];
    int bid = blockIdx.x;
    const float* src; _Float16* dst; int R, C, tr, tc;
    if (bid < 48)       { src = Wa;   dst = WaT;   R = 768; C = 256; int i = bid;       tr = i >> 2; tc = i & 3; }
    else if (bid < 96)  { src = Wv;   dst = WvT;   R = 768; C = 256; int i = bid - 48;  tr = i >> 2; tc = i & 3; }
    else if (bid < 112) { src = corr; dst = corrT; R = 256; C = 256; int i = bid - 96;  tr = i >> 2; tc = i & 3; }
    else                { src = Wb;   dst = WbT;   R = 512; C = 64;  int i = bid - 112; tr = i;      tc = 0;     }
    int r0 = tr * 64, c0 = tc * 64;
    int t = threadIdx.x;
    #pragma unroll
    for (int it = 0; it < 16; ++it) {
        int idx = t + it * 256;
        int r = idx >> 6, c = idx & 63;
        tile[r][c] = (_Float16)src[(size_t)(r0 + r) * C + (c0 + c)];
    }
    __syncthreads();
    #pragma unroll
    for (int it = 0; it < 16; ++it) {
        int idx = t + it * 256;
        int c = idx >> 6, r = idx & 63;
        dst[(size_t)(c0 + c) * R + (r0 + r)] = tile[r][c];
    }
}

// =========================================================
// k_proj v2: 2-phase double-buffered pipeline.
//  BM=128, BN=128, BK=32. A (fp32) -> LDS via global_load_lds
//  with pre-swizzled source (chunk kc ^= row&7); cvt to fp16 at
//  fragment build. B (fp16, L2-resident) loaded per-lane to regs.
//  4 waves (2x2), wave tile 64x64. Grid: 1024 blocks 1-D,
//  bijective XCD swizzle; n-half fastest so A panel shared in L2.
// =========================================================
__global__ __launch_bounds__(256, 3) void k_proj(
    const float* __restrict__ Xa, const float* __restrict__ Xv,
    const _Float16* __restrict__ WaT, const _Float16* __restrict__ WvT,
    const float* __restrict__ ba, const float* __restrict__ bv,
    _Float16* __restrict__ Aout, _Float16* __restrict__ Vout)
{
    __shared__ __align__(16) char sm[2][16384];   // A dbuf: 128 rows x 8 chunks x 16 B

    // decode swizzled block id: XCD gets contiguous chunk; n fastest, then z, then m
    int bid = blockIdx.x;                       // 0..1023
    int swz = ((bid & 7) << 7) | (bid >> 3);
    int mb = swz >> 2;
    int z  = (swz >> 1) & 1;
    int nb = swz & 1;
    const int m0 = mb * 128, n0 = nb * 128;

    const float*    X    = z ? Xv  : Xa;
    const _Float16* WT   = z ? WvT : WaT;
    const float*    bias = z ? bv  : ba;
    _Float16*       Out  = z ? Vout : Aout;

    const int t = threadIdx.x;
    const int lane = t & 63, w = t >> 6;
    const int wr = w >> 1, wc = w & 1;
    const int q = lane >> 4, lm = lane & 15;

    f32x4 acc[4][4] = {};

    // ---- stage one 128x32 fp32 A-tile into LDS buf (async, swizzled src) ----
    auto stage_A = [&](int k0, char* buf) {
        #pragma unroll
        for (int it = 0; it < 4; ++it) {
            int cbase = w * 256 + it * 64;
            char* lbase = buf + cbase * 16;          // wave-uniform LDS base
            int c = cbase + lane;
            int row = c >> 3;
            int kc = (c & 7) ^ (row & 7);            // inverse swizzle on source
            gl_lds16(X + (size_t)(m0 + row) * 768 + k0 + kc * 4, lbase);
        }
    };

    stage_A(0, sm[0]);
    __syncthreads();   // drains vmcnt(0): buf0 ready

    for (int ks = 0; ks < 24; ++ks) {
        if (ks + 1 < 24) stage_A((ks + 1) * 32, sm[(ks + 1) & 1]);

        // B fragments straight from global (L2-hit)
        f16x8 bf[4];
        #pragma unroll
        for (int nf = 0; nf < 4; ++nf)
            bf[nf] = *reinterpret_cast<const f16x8*>(
                WT + (size_t)(n0 + wc * 64 + nf * 16 + lm) * 768 + ks * 32 + q * 8);

        const char* Ac = sm[ks & 1];
        f16x8 af[4];
        #pragma unroll
        for (int mf = 0; mf < 4; ++mf) {
            int row = wr * 64 + mf * 16 + lm;
            const char* base = Ac + row * 128;
            int c0 = (2 * q) ^ (row & 7);
            int c1 = (2 * q + 1) ^ (row & 7);
            f32x4 lo = *reinterpret_cast<const f32x4*>(base + c0 * 16);
            f32x4 hi = *reinterpret_cast<const f32x4*>(base + c1 * 16);
            f16x4 l4 = __builtin_convertvector(lo, f16x4);
            f16x4 h4 = __builtin_convertvector(hi, f16x4);
            af[mf] = __builtin_shufflevector(l4, h4, 0, 1, 2, 3, 4, 5, 6, 7);
        }
        #pragma unroll
        for (int nf = 0; nf < 4; ++nf)
            #pragma unroll
            for (int mf = 0; mf < 4; ++mf)
                acc[mf][nf] = __builtin_amdgcn_mfma_f32_16x16x32_f16(af[mf], bf[nf], acc[mf][nf], 0, 0, 0);

        __syncthreads();   // drains vmcnt(0): next buf ready; all reads of cur done
    }

    // ---- epilogue: acc (+bias) -> LDS fp16 [128][128] -> coalesced stores ----
    float biasv[4];
    #pragma unroll
    for (int nf = 0; nf < 4; ++nf)
        biasv[nf] = bias[n0 + wc * 64 + nf * 16 + lm];

    _Float16* Os = (_Float16*)sm;   // 32 KB, reuse both A buffers
    #pragma unroll
    for (int mf = 0; mf < 4; ++mf)
        #pragma unroll
        for (int nf = 0; nf < 4; ++nf)
            #pragma unroll
            for (int r = 0; r < 4; ++r)
                Os[(wr * 64 + mf * 16 + q * 4 + r) * 128 + wc * 64 + nf * 16 + lm] =
                    (_Float16)(acc[mf][nf][r] + biasv[nf]);
    __syncthreads();
    #pragma unroll
    for (int it = 0; it < 8; ++it) {
        int idx = t + it * 256;
        int row = idx >> 4, c16 = idx & 15;
        f16x8 vdat = *reinterpret_cast<const f16x8*>(Os + row * 128 + c16 * 8);
        *reinterpret_cast<f16x8*>(Out + (size_t)(m0 + row) * 256 + n0 + c16 * 8) = vdat;
    }
}

// =========================================================
// k_fuse: per-batch (512 blocks, 256 thr = 4 waves) — unchanged
// =========================================================
#define SM_A    0u
#define SM_V    33792u
#define SM_AC   67584u
#define SM_CC   101376u
#define SM_ATA  118272u
#define SM_ATV  127488u
#define SM_AWT  136704u
#define SM_VWT  145920u
#define SM_RED  155136u
#define SM_TOTAL 159232u

__global__ __launch_bounds__(256) void k_fuse(
    const _Float16* __restrict__ A16, const _Float16* __restrict__ V16,
    const _Float16* __restrict__ corrT, const _Float16* __restrict__ WbT,
    const float* __restrict__ bb, const float* __restrict__ gamma,
    const float* __restrict__ beta, float* __restrict__ out)
{
    extern __shared__ char sm[];
    _Float16* a_s   = (_Float16*)(sm + SM_A);
    _Float16* v_s   = (_Float16*)(sm + SM_V);
    _Float16* ac_s  = (_Float16*)(sm + SM_AC);
    float*    cc_s  = (float*)(sm + SM_CC);
    _Float16* attAT = (_Float16*)(sm + SM_ATA);
    _Float16* attV  = (_Float16*)(sm + SM_ATV);
    _Float16* awT   = (_Float16*)(sm + SM_AWT);
    _Float16* vwT   = (_Float16*)(sm + SM_VWT);
    float*    red   = (float*)(sm + SM_RED);

    const int b = blockIdx.x;
    const int t = threadIdx.x, lane = t & 63, w = t >> 6;
    const int q = lane >> 4, lm = lane & 15;

    const _Float16* Ab = A16 + (size_t)b * 64 * 256;
    const _Float16* Vb = V16 + (size_t)b * 64 * 256;
    #pragma unroll
    for (int it = 0; it < 8; ++it) {
        int idx = t + it * 256;
        int row = idx >> 5, kc = idx & 31;
        *reinterpret_cast<f16x8*>(a_s + row * 264 + kc * 8) =
            *reinterpret_cast<const f16x8*>(Ab + row * 256 + kc * 8);
        *reinterpret_cast<f16x8*>(v_s + row * 264 + kc * 8) =
            *reinterpret_cast<const f16x8*>(Vb + row * 256 + kc * 8);
    }
    __syncthreads();

    // ac = a @ corr
    {
        f32x4 acc[4][4] = {};
        for (int ks = 0; ks < 8; ++ks) {
            f16x8 af[4];
            #pragma unroll
            for (int mf = 0; mf < 4; ++mf)
                af[mf] = *reinterpret_cast<const f16x8*>(a_s + (mf * 16 + lm) * 264 + ks * 32 + q * 8);
            #pragma unroll
            for (int nf = 0; nf < 4; ++nf) {
                int e = w * 64 + nf * 16 + lm;
                f16x8 bf = *reinterpret_cast<const f16x8*>(corrT + (size_t)e * 256 + ks * 32 + q * 8);
                #pragma unroll
                for (int mf = 0; mf < 4; ++mf)
                    acc[mf][nf] = __builtin_amdgcn_mfma_f32_16x16x32_f16(af[mf], bf, acc[mf][nf], 0, 0, 0);
            }
        }
        #pragma unroll
        for (int mf = 0; mf < 4; ++mf)
            #pragma unroll
            for (int nf = 0; nf < 4; ++nf)
                #pragma unroll
                for (int r = 0; r < 4; ++r)
                    ac_s[(mf * 16 + 4 * q + r) * 264 + (w * 64 + nf * 16 + lm)] = (_Float16)acc[mf][nf][r];
    }
    __syncthreads();

    // cc = ac @ v^T
    {
        f32x4 acc[4] = {};
        for (int ks = 0; ks < 8; ++ks) {
            f16x8 bf = *reinterpret_cast<const f16x8*>(v_s + (w * 16 + lm) * 264 + ks * 32 + q * 8);
            #pragma unroll
            for (int mf = 0; mf < 4; ++mf) {
                f16x8 af = *reinterpret_cast<const f16x8*>(ac_s + (mf * 16 + lm) * 264 + ks * 32 + q * 8);
                acc[mf] = __builtin_amdgcn_mfma_f32_16x16x32_f16(af, bf, acc[mf], 0, 0, 0);
            }
        }
        #pragma unroll
        for (int mf = 0; mf < 4; ++mf)
            #pragma unroll
            for (int r = 0; r < 4; ++r)
                cc_s[(mf * 16 + 4 * q + r) * 66 + (w * 16 + lm)] = acc[mf][r];
    }
    __syncthreads();

    // dual softmax (+identity)
    {
        int j = t & 63, seg = w;
        float cmx = -1e30f, rmx = -1e30f;
        #pragma unroll
        for (int k = 0; k < 16; ++k) {
            int i = seg * 16 + k;
            cmx = fmaxf(cmx, cc_s[i * 66 + j]);
            rmx = fmaxf(rmx, cc_s[j * 66 + i]);
        }
        red[0 * 256 + seg * 64 + j] = cmx;
        red[2 * 256 + seg * 64 + j] = rmx;
        __syncthreads();
        float cm = fmaxf(fmaxf(red[0 * 256 + 0 * 64 + j], red[0 * 256 + 1 * 64 + j]),
                         fmaxf(red[0 * 256 + 2 * 64 + j], red[0 * 256 + 3 * 64 + j]));
        float rm = fmaxf(fmaxf(red[2 * 256 + 0 * 64 + j], red[2 * 256 + 1 * 64 + j]),
                         fmaxf(red[2 * 256 + 2 * 64 + j], red[2 * 256 + 3 * 64 + j]));
        float cs = 0.f, rs = 0.f;
        #pragma unroll
        for (int k = 0; k < 16; ++k) {
            int i = seg * 16 + k;
            cs += __expf(cc_s[i * 66 + j] - cm);
            rs += __expf(cc_s[j * 66 + i] - rm);
        }
        red[1 * 256 + seg * 64 + j] = cs;
        red[3 * 256 + seg * 64 + j] = rs;
        __syncthreads();
        float csum = red[1 * 256 + 0 * 64 + j] + red[1 * 256 + 1 * 64 + j] +
                     red[1 * 256 + 2 * 64 + j] + red[1 * 256 + 3 * 64 + j];
        float rsum = red[3 * 256 + 0 * 64 + j] + red[3 * 256 + 1 * 64 + j] +
                     red[3 * 256 + 2 * 64 + j] + red[3 * 256 + 3 * 64 + j];
        float cinv = 1.f / csum, rinv = 1.f / rsum;
        #pragma unroll
        for (int k = 0; k < 16; ++k) {
            int i = seg * 16 + k;
            float pa = __expf(cc_s[i * 66 + j] - cm) * cinv;
            if (i == j) pa += 1.f;
            attAT[j * 72 + i] = (_Float16)pa;
            float pv = __expf(cc_s[j * 66 + i] - rm) * rinv;
            if (i == j) pv += 1.f;
            attV[j * 72 + i] = (_Float16)pv;
        }
    }

    // aw = a@Wb_top (waves 0,1), vw = v@Wb_bot (waves 2,3)
    {
        int isV = w >> 1, wcol = w & 1;
        const _Float16* src = isV ? v_s : a_s;
        const int doff = isV ? 256 : 0;
        f32x4 acc[4][2] = {};
        for (int ks = 0; ks < 8; ++ks) {
            f16x8 af[4];
            #pragma unroll
            for (int mf = 0; mf < 4; ++mf)
                af[mf] = *reinterpret_cast<const f16x8*>(src + (mf * 16 + lm) * 264 + ks * 32 + q * 8);
            #pragma unroll
            for (int nf = 0; nf < 2; ++nf) {
                int o = wcol * 32 + nf * 16 + lm;
                f16x8 bf = *reinterpret_cast<const f16x8*>(WbT + (size_t)o * 512 + doff + ks * 32 + q * 8);
                #pragma unroll
                for (int mf = 0; mf < 4; ++mf)
                    acc[mf][nf] = __builtin_amdgcn_mfma_f32_16x16x32_f16(af[mf], bf, acc[mf][nf], 0, 0, 0);
            }
        }
        _Float16* dst = isV ? vwT : awT;
        #pragma unroll
        for (int mf = 0; mf < 4; ++mf)
            #pragma unroll
            for (int nf = 0; nf < 2; ++nf)
                #pragma unroll
                for (int r = 0; r < 4; ++r)
                    dst[(wcol * 32 + nf * 16 + lm) * 72 + (mf * 16 + 4 * q + r)] = (_Float16)acc[mf][nf][r];
    }
    __syncthreads();

    // h = attA^T@aw + attV@vw
    f32x4 hacc[4] = {};
    #pragma unroll
    for (int kk = 0; kk < 2; ++kk) {
        f16x8 a1 = *reinterpret_cast<const f16x8*>(attAT + (16 * w + lm) * 72 + kk * 32 + q * 8);
        f16x8 a2 = *reinterpret_cast<const f16x8*>(attV  + (16 * w + lm) * 72 + kk * 32 + q * 8);
        #pragma unroll
        for (int nf = 0; nf < 4; ++nf) {
            f16x8 b1 = *reinterpret_cast<const f16x8*>(awT + (nf * 16 + lm) * 72 + kk * 32 + q * 8);
            f16x8 b2 = *reinterpret_cast<const f16x8*>(vwT + (nf * 16 + lm) * 72 + kk * 32 + q * 8);
            hacc[nf] = __builtin_amdgcn_mfma_f32_16x16x32_f16(a1, b1, hacc[nf], 0, 0, 0);
            hacc[nf] = __builtin_amdgcn_mfma_f32_16x16x32_f16(a2, b2, hacc[nf], 0, 0, 0);
        }
    }

    // +bb, LayerNorm, ReLU, store
    {
        float bbv[4], gv[4], bev[4];
        #pragma unroll
        for (int nf = 0; nf < 4; ++nf) {
            int o = nf * 16 + lm;
            bbv[nf] = bb[o]; gv[nf] = gamma[o]; bev[nf] = beta[o];
        }
        #pragma unroll
        for (int r = 0; r < 4; ++r) {
            float vals[4]; float s1 = 0.f, s2 = 0.f;
            #pragma unroll
            for (int nf = 0; nf < 4; ++nf) {
                float hv = hacc[nf][r] + bbv[nf];
                vals[nf] = hv; s1 += hv; s2 += hv * hv;
            }
            #pragma unroll
            for (int m = 1; m < 16; m <<= 1) {
                s1 += __shfl_xor(s1, m, 64);
                s2 += __shfl_xor(s2, m, 64);
            }
            float mu = s1 * 0.015625f;
            float var = s2 * 0.015625f - mu * mu;
            float rstd = rsqrtf(var + 1e-5f);
            int s = 16 * w + 4 * q + r;
            float* orow = out + ((size_t)b * 64 + s) * 64;
            #pragma unroll
            for (int nf = 0; nf < 4; ++nf) {
                float y = (vals[nf] - mu) * rstd * gv[nf] + bev[nf];
                orow[nf * 16 + lm] = fmaxf(y, 0.f);
            }
        }
    }
}

// =========================================================
extern "C" void kernel_launch(void* const* d_in, const int* in_sizes, int n_in,
                              void* d_out, int out_size, void* d_ws, size_t ws_size,
                              hipStream_t stream) {
    const float* Xa    = (const float*)d_in[0];
    const float* Xv    = (const float*)d_in[1];
    const float* Wa    = (const float*)d_in[2];
    const float* ba    = (const float*)d_in[3];
    const float* Wv    = (const float*)d_in[4];
    const float* bv    = (const float*)d_in[5];
    const float* corr  = (const float*)d_in[6];
    const float* Wb    = (const float*)d_in[7];
    const float* bb    = (const float*)d_in[8];
    const float* gamma = (const float*)d_in[9];
    const float* beta  = (const float*)d_in[10];
    float* out = (float*)d_out;
    char* ws = (char*)d_ws;

    _Float16* a16   = (_Float16*)(ws + A16_OFF);
    _Float16* v16   = (_Float16*)(ws + V16_OFF);
    _Float16* WaT   = (_Float16*)(ws + WAT_OFF);
    _Float16* WvT   = (_Float16*)(ws + WVT_OFF);
    _Float16* corrT = (_Float16*)(ws + CORRT_OFF);
    _Float16* WbT   = (_Float16*)(ws + WBT_OFF);

    hipLaunchKernelGGL(k_tr, dim3(120), dim3(256), 0, stream,
                       Wa, Wv, corr, Wb, WaT, WvT, corrT, WbT);
    hipLaunchKernelGGL(k_proj, dim3(1024), dim3(256), 0, stream,
                       Xa, Xv, WaT, WvT, ba, bv, a16, v16);
    (void)hipFuncSetAttribute((const void*)k_fuse,
                              hipFuncAttributeMaxDynamicSharedMemorySize, SM_TOTAL);
    hipLaunchKernelGGL(k_fuse, dim3(512), dim3(256), SM_TOTAL, stream,
                       a16, v16, corrT, WbT, bb, gamma, beta, out);
}